// Round 2
// baseline (853.166 us; speedup 1.0000x reference)
//
#include <hip/hip_runtime.h>
#include <hip/hip_bf16.h>
#include <math.h>

// Problem constants
#define BATCH 16
#define G 5           // feature groups
#define CI 4          // in channels per group  (20/5)
#define CO 8          // out channels per group (40/5)
#define HW 384
#define KK 5          // padded kernel size (MAXK)
#define PADD 2

// Weight layout in workspace: [G][CI][KY][KX][CO]  (CO contiguous) = 4000 floats

__global__ void gen_weights(const float* __restrict__ alphas,
                            const float* __restrict__ scales,
                            float* __restrict__ w) {
    int idx = blockIdx.x * blockDim.x + threadIdx.x;
    if (idx >= G * CI * KK * KK) return;   // 500
    int kx = idx % 5; int r = idx / 5;
    int ky = r % 5;   r /= 5;
    int i  = r % 4;   int s = r / 4;

    float mn = 0.2f * (float)s;
    float mx = mn + 0.2f;
    float sigma = 0.5f * (mx - mn) * tanhf(scales[s]) + 0.5f * (mn + mx);
    int fs = (s < 3) ? 1 : 2;          // static half filter sizes [1,1,1,2,2]
    int p  = 2 - fs;                   // zero-pad to 5x5

    float outw[CO];
    bool valid = (ky >= p) && (ky < 5 - p) && (kx >= p) && (kx < 5 - p);
    if (!valid) {
        #pragma unroll
        for (int o = 0; o < CO; ++o) outw[o] = 0.f;
    } else {
        float inv2s2 = 1.f / (2.f * sigma * sigma);
        float Gs = 0.f;
        for (int t = -fs; t <= fs; ++t) Gs += expf(-(float)(t * t) * inv2s2);
        const float sqrt2 = 1.41421356237309505f;
        float c = -1.f / (sigma * sqrt2);

        float xy = (float)(ky - p - fs);
        float xx = (float)(kx - p - fs);

        float gy = expf(-xy * xy * inv2s2) / Gs;
        float gx = expf(-xx * xx * inv2s2) / Gs;
        float uy = xy / (sigma * sqrt2);
        float ux = xx / (sigma * sqrt2);

        float dy[3], dx[3];
        dy[0] = gy;
        dy[1] = c * 2.f * uy * gy;
        dy[2] = c * c * (4.f * uy * uy - 2.f) * gy;
        dx[0] = gx;
        dx[1] = c * 2.f * ux * gx;
        dx[2] = c * c * (4.f * ux * ux - 2.f) * gx;

        float bas[6];
        bas[0] = dy[0] * dx[0];
        bas[1] = dy[0] * dx[1];
        bas[2] = dy[0] * dx[2];
        bas[3] = dy[1] * dx[0];
        bas[4] = dy[1] * dx[1];
        bas[5] = dy[2] * dx[0];

        #pragma unroll
        for (int o = 0; o < CO; ++o) {
            float acc = 0.f;
            #pragma unroll
            for (int n = 0; n < 6; ++n)
                acc += bas[n] * alphas[((s * 6 + n) * CI + i) * CO + o];
            outw[o] = acc;
        }
    }
    float* dst = w + ((((s * CI + i) * KK + ky) * KK + kx) * CO);
    #pragma unroll
    for (int o = 0; o < CO; ++o) dst[o] = outw[o];
}

// Conv: 32x32 output tile per block, 256 threads.
// Thread = (oc low 3 bits, pixel block high 5 bits): 1 oc x 4y x 8x outputs.
// Weights + input rows register-resident per input channel.
#define TLE 32
#define ITY 36          // input tile rows with halo
#define SSTR 40         // LDS row stride (floats), 16B-aligned rows

__global__ __launch_bounds__(256) void conv_kernel(const float* __restrict__ in,
                                                   const float* __restrict__ w,
                                                   float* __restrict__ out) {
    __shared__ float s_in[CI][ITY][SSTR];     // 4*36*40*4 = 23040 B
    __shared__ float s_w[CO][CI][28];         // 3584 B (25 used, pad to 28 for b128)

    const int tileX = blockIdx.x * TLE;
    const int tileY = blockIdx.y * TLE;
    const int bz = blockIdx.z;           // b*G + g
    const int g = bz % G;
    const int b = bz / G;
    const int tid = threadIdx.x;

    // stage weights: w[g][i][k(=ky*5+kx)][oc] -> s_w[oc][i][k]
    const float* wg = w + g * (CI * KK * KK * CO);
    for (int l = tid; l < CI * KK * KK * CO; l += 256) {
        int oc = l & 7;
        int r = l >> 3;            // i*25 + k
        int i = r / 25;
        int k = r - i * 25;
        s_w[oc][i][k] = wg[(i * 25 + k) * CO + oc];
    }

    // stage input tile (zero halo at borders)
    const float* inb = in + ((size_t)b * (G * CI) + g * CI) * (HW * HW);
    for (int l = tid; l < CI * 36 * 36; l += 256) {
        int c = l / (36 * 36);
        int r = l - c * (36 * 36);
        int ly = r / 36;
        int lx = r - ly * 36;
        int gy = tileY - PADD + ly;
        int gx = tileX - PADD + lx;
        float v = 0.f;
        if ((unsigned)gy < (unsigned)HW && (unsigned)gx < (unsigned)HW)
            v = inb[c * (HW * HW) + gy * HW + gx];
        s_in[c][ly][lx] = v;
    }
    __syncthreads();

    const int oc  = tid & 7;
    const int pix = tid >> 3;        // 0..31
    const int yb  = pix >> 2;        // 0..7
    const int xc  = pix & 3;         // 0..3
    const int ty0 = yb * 4;
    const int xl0 = xc * 8;

    float acc[4][8];
    #pragma unroll
    for (int oy = 0; oy < 4; ++oy)
        #pragma unroll
        for (int x = 0; x < 8; ++x) acc[oy][x] = 0.f;

    for (int i = 0; i < CI; ++i) {
        // 8 input rows x 12 floats -> registers (halo coords: rows ty0..ty0+7, cols xl0..xl0+11)
        float rbuf[8][12];
        #pragma unroll
        for (int rr = 0; rr < 8; ++rr) {
            const float* p = &s_in[i][ty0 + rr][xl0];
            float4 a = *(const float4*)(p);
            float4 bq = *(const float4*)(p + 4);
            float4 cq = *(const float4*)(p + 8);
            rbuf[rr][0] = a.x;  rbuf[rr][1] = a.y;  rbuf[rr][2]  = a.z;  rbuf[rr][3]  = a.w;
            rbuf[rr][4] = bq.x; rbuf[rr][5] = bq.y; rbuf[rr][6]  = bq.z; rbuf[rr][7]  = bq.w;
            rbuf[rr][8] = cq.x; rbuf[rr][9] = cq.y; rbuf[rr][10] = cq.z; rbuf[rr][11] = cq.w;
        }
        // 25 weights -> registers (7 aligned b128 reads over the 28-float slot)
        float wv[28];
        #pragma unroll
        for (int q = 0; q < 7; ++q) {
            float4 t = *(const float4*)(&s_w[oc][i][4 * q]);
            wv[4 * q + 0] = t.x; wv[4 * q + 1] = t.y;
            wv[4 * q + 2] = t.z; wv[4 * q + 3] = t.w;
        }

        #pragma unroll
        for (int ky = 0; ky < KK; ++ky) {
            #pragma unroll
            for (int oy = 0; oy < 4; ++oy) {
                #pragma unroll
                for (int kx = 0; kx < KK; ++kx) {
                    float wgt = wv[ky * 5 + kx];
                    #pragma unroll
                    for (int x = 0; x < 8; ++x)
                        acc[oy][x] = fmaf(wgt, rbuf[oy + ky][kx + x], acc[oy][x]);
                }
            }
        }
    }

    // write 4 rows x 8 consecutive floats for this oc
    const int oy0 = tileY + ty0;
    float* outb = out + (((size_t)b * (G * CO) + (size_t)g * CO + oc) * HW + oy0) * HW + tileX + xl0;
    #pragma unroll
    for (int oy = 0; oy < 4; ++oy) {
        float4 r0, r1;
        r0.x = acc[oy][0]; r0.y = acc[oy][1]; r0.z = acc[oy][2]; r0.w = acc[oy][3];
        r1.x = acc[oy][4]; r1.y = acc[oy][5]; r1.z = acc[oy][6]; r1.w = acc[oy][7];
        *(float4*)(outb + (size_t)oy * HW) = r0;
        *(float4*)(outb + (size_t)oy * HW + 4) = r1;
    }
}

extern "C" void kernel_launch(void* const* d_in, const int* in_sizes, int n_in,
                              void* d_out, int out_size, void* d_ws, size_t ws_size,
                              hipStream_t stream) {
    const float* data   = (const float*)d_in[0];
    const float* alphas = (const float*)d_in[1];
    const float* scales = (const float*)d_in[2];
    float* out = (float*)d_out;
    float* w   = (float*)d_ws;   // 4000 floats = 16 KB

    gen_weights<<<2, 256, 0, stream>>>(alphas, scales, w);

    dim3 grid(HW / TLE, HW / TLE, BATCH * G);   // (12, 12, 80)
    conv_kernel<<<grid, 256, 0, stream>>>(data, w, out);
}